// Round 10
// baseline (444.912 us; speedup 1.0000x reference)
//
#include <hip/hip_runtime.h>
#include <cstdint>
#include <cstddef>

#define NPTS 8192
#define NUM_CLASSES 5
#define XCOLS 10          // 3 coords + batch + feat + 5 seg
#define EPS2 225.0f
#define MIN_PTS 5
#define NGROUPS 10
#define BIGC 0x3fffffff

#define NLCAP 1536        // max nodes per group (expect ~820)
#define EACAP 8192        // all same-group eps-pairs u<v (expect ~5.4k)
#define ELCAP 8192        // core-core edges
#define EBCAP 2048        // core-noncore edges (expect ~500)
#define ROUNDS 24
#define KR 8              // row strips per super-strip (8*128 = 1024 rows)

// ---------------- setup: pack coords+p2, compute group ----------------
__global__ void k_setup(const float* __restrict__ x, float4* __restrict__ q,
                        int* __restrict__ grp) {
    int i = blockIdx.x * blockDim.x + threadIdx.x;
    if (i >= NPTS) return;
    const float* r = x + (size_t)i * XCOLS;
    float px = r[0], py = r[1], pz = r[2];
    int b = (int)r[3];
    float best = r[5]; int bc = 0;
    #pragma unroll
    for (int c = 1; c < NUM_CLASSES; c++) {
        float v = r[5 + c];
        if (v > best) { best = v; bc = c; }   // strict > keeps first max (jnp.argmax)
    }
    q[i] = make_float4(px, py, pz, px*px + py*py + pz*pz);
    grp[i] = b * NUM_CLASSES + bc;
}

// ---------------- per-group: adjacency + DBSCAN entirely in LDS --------------
// one block (1024 thr = 16 waves) per group. ~820 pts -> 0.67M pair evals.
// Pair pass: replica g=tid>>7 owns chunks c==g (mod 8); thread owns rows
// r0+128k in registers -> each broadcast LDS read feeds 64 lanes x ~7 rows.
__global__ void __launch_bounds__(1024) k_group(
        const float4* __restrict__ q, const int* __restrict__ grp,
        const float* __restrict__ x, float* __restrict__ out) {
    __shared__ float4 pts[NLCAP];                    // 24 KB
    __shared__ int nlist[NLCAP];                     // 6 KB (global idx, ASCENDING)
    __shared__ int sdeg[NLCAP];                      // 6 KB
    __shared__ int spar[NLCAP];                      // 6 KB (label -> later ccid)
    __shared__ int scid[NLCAP];                      // 6 KB
    __shared__ int sbmin[NLCAP];                     // 6 KB
    __shared__ unsigned int eAll[EACAP];             // 32 KB
    __shared__ unsigned int eL[ELCAP];               // 32 KB
    __shared__ unsigned int eB[EBCAP];               // 8 KB
    __shared__ unsigned long long corebm[NLCAP/64];  // 192 B
    __shared__ unsigned long long repbm[NLCAP/64];   // 192 B
    __shared__ int nNodes, nAll, nL, nB, sflag;

    const int g = blockIdx.x;
    const int tid = threadIdx.x, lane = tid & 63, wv = tid >> 6;

    if (tid == 0) { nNodes = 0; nAll = 0; nL = 0; nB = 0; }
    __syncthreads();

    // ordered node list (wave 0 serial ballot scan -> local order == index order)
    if (wv == 0) {
        int running = 0;
        for (int w = 0; w < NPTS / 64; w++) {
            int i = w * 64 + lane;
            bool ing = (grp[i] == g);
            unsigned long long bm = __ballot(ing);
            if (ing) {
                int p = running + __popcll(bm & ((1ull << lane) - 1ull));
                if (p < NLCAP) nlist[p] = i;
            }
            running += __popcll(bm);
        }
        if (lane == 0) nNodes = (running > NLCAP) ? NLCAP : running;
    }
    __syncthreads();
    const int NN = nNodes;

    // gather points; init state; sentinel-pad so pair loop needs no bounds checks
    for (int k = tid; k < NLCAP; k += 1024) {
        if (k < NN) {
            pts[k] = q[nlist[k]];
            sdeg[k] = 1;            // self-adjacency
            spar[k] = k;
            sbmin[k] = BIGC;
        } else {
            pts[k] = make_float4(0.f, 0.f, 0.f, 3.0e38f);  // d2 huge -> never adjacent
        }
    }
    __syncthreads();

    // ---- pair pass ----
    const int NC = ((NN + 31) & ~31) >> 5;           // 32-wide v-chunks
    const int ROWSPAN = (NN + 127) & ~127;           // rows padded to 128
    const int rep = tid >> 7;                        // replica 0..7 (chunk subset)
    const int r0  = tid & 127;
    for (int s = 0; s < ROWSPAN; s += KR * 128) {    // one iter when NN <= 1024
        int KRs = (ROWSPAN - s) >> 7; if (KRs > KR) KRs = KR;
        float4 qu[KR]; int rowdeg[KR];
        for (int k = 0; k < KRs; k++) { qu[k] = pts[s + r0 + 128 * k]; rowdeg[k] = 0; }

        for (int c = rep; c < NC; c += 8) {
            int base = c << 5;
            unsigned int bits[KR];
            for (int k = 0; k < KRs; k++) bits[k] = 0u;
            #pragma unroll
            for (int t = 0; t < 32; t++) {
                float4 qv = pts[base + t];           // wave-uniform -> LDS broadcast
                for (int k = 0; k < KRs; k++) {
                    float d2 = qu[k].w + qv.w - 2.0f * (qu[k].x*qv.x + qu[k].y*qv.y + qu[k].z*qv.z);
                    bits[k] |= (d2 < EPS2) ? (1u << t) : 0u;
                }
            }
            int cnt = 0;
            for (int k = 0; k < KRs; k++) {
                int d = (s + r0 + 128 * k) - base;   // keep only v > u
                if (d >= 31) bits[k] = 0u;
                else if (d >= 0) bits[k] &= ~((2u << d) - 1u);
                int pc = __popc(bits[k]);
                rowdeg[k] += pc;
                cnt += pc;
            }
            // wave-aggregated reservation (one LDS atomic per wave-chunk)
            int incl = cnt;
            #pragma unroll
            for (int st = 1; st < 64; st <<= 1) {
                int o = __shfl_up(incl, st);
                if (lane >= st) incl += o;
            }
            int tot = __shfl(incl, 63);
            if (tot > 0) {
                int rbase = 0;
                if (lane == 63) rbase = atomicAdd(&nAll, tot);
                rbase = __shfl(rbase, 63);
                int p = rbase + incl - cnt;
                for (int k = 0; k < KRs; k++) {
                    unsigned int b = bits[k];
                    unsigned int uhi = (unsigned int)(s + r0 + 128 * k) << 11;
                    while (b) {
                        int t = __ffs(b) - 1; b &= b - 1;
                        if (p < EACAP) eAll[p] = uhi | (unsigned int)(base + t);
                        p++;
                    }
                }
            }
        }
        for (int k = 0; k < KRs; k++)
            if (rowdeg[k] > 0) atomicAdd(&sdeg[s + r0 + 128 * k], rowdeg[k]);
    }
    __syncthreads();
    const int NA = (nAll > EACAP) ? EACAP : nAll;

    // v-side degrees (scattered LDS atomics over ~820 addresses)
    for (int e = tid; e < NA; e += 1024)
        atomicAdd(&sdeg[eAll[e] & 2047u], 1);
    __syncthreads();

    // core bitmap (local indices)
    for (int w = wv; w < NLCAP / 64; w += 16) {
        int l = w * 64 + lane;
        bool isc = (l < NN) && (sdeg[l] >= MIN_PTS);
        unsigned long long bm = __ballot(isc);
        if (lane == 0) corebm[w] = bm;
    }
    __syncthreads();
    auto corebit = [&](int l) -> bool { return (corebm[l >> 6] >> (l & 63)) & 1ull; };

    // classify eAll -> eL (core-core) / eB (core-noncore), wave-aggregated
    for (int e0 = 0; e0 < NA; e0 += 1024) {
        int e = e0 + tid;
        unsigned int pk = (e < NA) ? eAll[e] : 0u;
        bool val = (e < NA);
        int u = (int)(pk >> 11), v = (int)(pk & 2047u);
        bool cu = val && corebit(u), cv = val && corebit(v);
        bool isL = cu && cv, isB = val && (cu != cv);
        unsigned long long mL = __ballot(isL);
        if (mL) {
            int b0 = 0;
            if (lane == 0) b0 = atomicAdd(&nL, __popcll(mL));
            b0 = __shfl(b0, 0);
            if (isL) {
                int idx = b0 + __popcll(mL & ((1ull << lane) - 1ull));
                if (idx < ELCAP) eL[idx] = pk;
            }
        }
        unsigned long long mB = __ballot(isB);
        if (mB) {
            int b0 = 0;
            if (lane == 0) b0 = atomicAdd(&nB, __popcll(mB));
            b0 = __shfl(b0, 0);
            if (isB) {
                int idx = b0 + __popcll(mB & ((1ull << lane) - 1ull));
                if (idx < EBCAP) eB[idx] = pk;
            }
        }
    }
    __syncthreads();
    const int NL = (nL > ELCAP) ? ELCAP : nL;
    const int NB = (nB > EBCAP) ? EBCAP : nB;

    // SV rounds: hook-to-min + pointer jump (fixpoint = component min index)
    for (int r = 0; r < ROUNDS; r++) {
        if (tid == 0) sflag = 0;
        __syncthreads();
        for (int k = tid; k < NL; k += 1024) {
            unsigned int pk = eL[k];
            int u = (int)(pk >> 11), v = (int)(pk & 2047u);
            int a = spar[u], b2 = spar[v];
            if (a < b2)      { int old = atomicMin(&spar[v], a);  if (old > a)  sflag = 1; }
            else if (b2 < a) { int old = atomicMin(&spar[u], b2); if (old > b2) sflag = 1; }
        }
        __syncthreads();
        for (int k = tid; k < NN; k += 1024) {
            int s = spar[k]; int s2 = spar[s];
            if (s2 < s) { spar[k] = s2; sflag = 1; }
        }
        __syncthreads();
        if (!sflag) break;
    }

    // reps + rank (local order == global index order -> cid = rank among reps)
    for (int w = wv; w < NLCAP / 64; w += 16) {
        int l = w * 64 + lane;
        bool isr = (l < NN) && corebit(l) && (spar[l] == l);
        unsigned long long bm = __ballot(isr);
        if (lane == 0) repbm[w] = bm;
    }
    __syncthreads();
    if (wv == 0) {
        int running = 0;
        for (int w = 0; w < NLCAP / 64; w++) {
            unsigned long long bm = repbm[w];
            if ((bm >> lane) & 1ull)
                scid[w * 64 + lane] = running + __popcll(bm & ((1ull << lane) - 1ull));
            running += __popcll(bm);
        }
    }
    __syncthreads();
    // ccid -> overwrite spar
    int cc[2];
    #pragma unroll
    for (int t = 0; t < 2; t++) {
        int k = tid + t * 1024;
        cc[t] = (k < NN && corebit(k)) ? scid[spar[k]] : BIGC;
    }
    __syncthreads();
    #pragma unroll
    for (int t = 0; t < 2; t++) {
        int k = tid + t * 1024;
        if (k < NN) spar[k] = cc[t];
    }
    __syncthreads();
    // border: min adjacent core cid for the non-core endpoint
    for (int k = tid; k < NB; k += 1024) {
        unsigned int pk = eB[k];
        int u = (int)(pk >> 11), v = (int)(pk & 2047u);
        int cu = spar[u], cv = spar[v];
        if (cu == BIGC) atomicMin(&sbmin[u], cv);
        else            atomicMin(&sbmin[v], cu);
    }
    __syncthreads();
    // final labels + clustered output for this group's nodes
    for (int k = tid; k < NN; k += 1024) {
        int i = nlist[k];
        int c = spar[k];
        int lbl = (c != BIGC) ? c : ((sbmin[k] < BIGC) ? sbmin[k] : -1);
        out[i] = (float)lbl;
        const float* r = x + (size_t)i * XCOLS;
        float* o = out + NPTS + (size_t)i * 5;
        bool keep = lbl >= 0;
        #pragma unroll
        for (int c5 = 0; c5 < 5; c5++) o[c5] = keep ? r[c5] : 0.0f;
    }
}

extern "C" void kernel_launch(void* const* d_in, const int* in_sizes, int n_in,
                              void* d_out, int out_size, void* d_ws, size_t ws_size,
                              hipStream_t stream) {
    const float* x = (const float*)d_in[0];
    float* out = (float*)d_out;
    char* ws = (char*)d_ws;

    // workspace: 164 KB total
    float4* q = (float4*)(ws);               // 131072 B
    int* grp  = (int*)(ws + 131072);         // 32768 B

    k_setup<<<NPTS / 256, 256, 0, stream>>>(x, q, grp);
    k_group<<<NGROUPS, 1024, 0, stream>>>(q, grp, x, out);
}

// Round 11
// 159.903 us; speedup vs baseline: 2.7824x; 2.7824x over previous
//
#include <hip/hip_runtime.h>
#include <cstdint>
#include <cstddef>

#define NPTS 8192
#define NUM_CLASSES 5
#define XCOLS 10          // 3 coords + batch + feat + 5 seg
#define EPS2 225.0f
#define MIN_PTS 5
#define NGROUPS 10
#define BIGC 0x3fffffff

#define NLCAP 1536        // max nodes per group (expect ~820)
#define EACAP 8192        // all same-group eps-pairs u<v (expect ~5.4k)
#define ELCAP 8192        // core-core edges
#define EBCAP 2048        // core-noncore edges (expect ~500)
#define ROUNDS 24
#define KR 12             // row strips per thread: 12*128 = NLCAP (COMPILE-TIME)

// ---------------- setup: pack coords+p2, compute group ----------------
__global__ void k_setup(const float* __restrict__ x, float4* __restrict__ q,
                        int* __restrict__ grp) {
    int i = blockIdx.x * blockDim.x + threadIdx.x;
    if (i >= NPTS) return;
    const float* r = x + (size_t)i * XCOLS;
    float px = r[0], py = r[1], pz = r[2];
    int b = (int)r[3];
    float best = r[5]; int bc = 0;
    #pragma unroll
    for (int c = 1; c < NUM_CLASSES; c++) {
        float v = r[5 + c];
        if (v > best) { best = v; bc = c; }   // strict > keeps first max (jnp.argmax)
    }
    q[i] = make_float4(px, py, pz, px*px + py*py + pz*pz);
    grp[i] = b * NUM_CLASSES + bc;
}

// ---------------- per-group: adjacency + DBSCAN entirely in LDS --------------
// one block (1024 thr = 16 waves) per group. ~820 pts -> ~0.75M pair evals.
// Pair pass: replica rep=tid>>7 owns chunks c==rep (mod 8); thread owns rows
// r0+128k (k<KR, COMPILE-TIME unrolled -> arrays stay in VGPRs, no scratch).
__global__ void __launch_bounds__(1024) k_group(
        const float4* __restrict__ q, const int* __restrict__ grp,
        const float* __restrict__ x, float* __restrict__ out) {
    __shared__ float4 pts[NLCAP];                    // 24 KB
    __shared__ int nlist[NLCAP];                     // 6 KB (global idx, ASCENDING)
    __shared__ int sdeg[NLCAP];                      // 6 KB
    __shared__ int spar[NLCAP];                      // 6 KB (label -> later ccid)
    __shared__ int scid[NLCAP];                      // 6 KB
    __shared__ int sbmin[NLCAP];                     // 6 KB
    __shared__ unsigned int eAll[EACAP];             // 32 KB
    __shared__ unsigned int eL[ELCAP];               // 32 KB
    __shared__ unsigned int eB[EBCAP];               // 8 KB
    __shared__ unsigned long long corebm[NLCAP/64];  // 192 B
    __shared__ unsigned long long repbm[NLCAP/64];   // 192 B
    __shared__ int nNodes, nAll, nL, nB, sflag;

    const int g = blockIdx.x;
    const int tid = threadIdx.x, lane = tid & 63, wv = tid >> 6;

    if (tid == 0) { nNodes = 0; nAll = 0; nL = 0; nB = 0; }
    __syncthreads();

    // ordered node list (wave 0 serial ballot scan -> local order == index order)
    if (wv == 0) {
        int running = 0;
        for (int w = 0; w < NPTS / 64; w++) {
            int i = w * 64 + lane;
            bool ing = (grp[i] == g);
            unsigned long long bm = __ballot(ing);
            if (ing) {
                int p = running + __popcll(bm & ((1ull << lane) - 1ull));
                if (p < NLCAP) nlist[p] = i;
            }
            running += __popcll(bm);
        }
        if (lane == 0) nNodes = (running > NLCAP) ? NLCAP : running;
    }
    __syncthreads();
    const int NN = nNodes;

    // gather points; init state; sentinel-pad so pair loop needs no bounds checks
    for (int k = tid; k < NLCAP; k += 1024) {
        if (k < NN) {
            pts[k] = q[nlist[k]];
            sdeg[k] = 1;            // self-adjacency
            spar[k] = k;
            sbmin[k] = BIGC;
        } else {
            pts[k] = make_float4(0.f, 0.f, 0.f, 3.0e38f);  // d2 huge -> never adjacent
        }
    }
    __syncthreads();

    // ---- pair pass (all array indices compile-time -> VGPRs) ----
    const int NC = ((NN + 31) & ~31) >> 5;           // 32-wide v-chunks
    const int ROWSPAN = (NN + 127) & ~127;           // multiple of 128
    const int rep = tid >> 7;                        // replica 0..7 (chunk subset)
    const int r0  = tid & 127;

    float4 qu[KR]; int rowdeg[KR];
    #pragma unroll
    for (int k = 0; k < KR; k++) {
        qu[k] = pts[r0 + 128 * k];                   // <= 1535, sentinel-padded
        rowdeg[k] = 0;
    }

    for (int c = rep; c < NC; c += 8) {
        int base = c << 5;
        unsigned int bits[KR];
        #pragma unroll
        for (int k = 0; k < KR; k++) bits[k] = 0u;
        #pragma unroll
        for (int t = 0; t < 32; t++) {
            float4 qv = pts[base + t];               // wave-uniform -> LDS broadcast
            #pragma unroll
            for (int k = 0; k < KR; k++) {
                if (128 * k < ROWSPAN) {             // wave-uniform strip guard
                    float d2 = qu[k].w + qv.w - 2.0f * (qu[k].x*qv.x + qu[k].y*qv.y + qu[k].z*qv.z);
                    bits[k] |= (d2 < EPS2) ? (1u << t) : 0u;
                }
            }
        }
        int cnt = 0;
        #pragma unroll
        for (int k = 0; k < KR; k++) {
            if (128 * k < ROWSPAN) {
                int d = (r0 + 128 * k) - base;       // keep only v > u
                if (d >= 31) bits[k] = 0u;
                else if (d >= 0) bits[k] &= ~((2u << d) - 1u);
                int pc = __popc(bits[k]);
                rowdeg[k] += pc;
                cnt += pc;
            }
        }
        // wave-aggregated reservation (one LDS atomic per wave-chunk)
        int incl = cnt;
        #pragma unroll
        for (int st = 1; st < 64; st <<= 1) {
            int o = __shfl_up(incl, st);
            if (lane >= st) incl += o;
        }
        int tot = __shfl(incl, 63);
        if (tot > 0) {
            int rbase = 0;
            if (lane == 63) rbase = atomicAdd(&nAll, tot);
            rbase = __shfl(rbase, 63);
            int p = rbase + incl - cnt;
            #pragma unroll
            for (int k = 0; k < KR; k++) {
                if (128 * k < ROWSPAN) {
                    unsigned int b = bits[k];
                    unsigned int uhi = (unsigned int)(r0 + 128 * k) << 11;
                    while (b) {
                        int t = __ffs(b) - 1; b &= b - 1;
                        if (p < EACAP) eAll[p] = uhi | (unsigned int)(base + t);
                        p++;
                    }
                }
            }
        }
    }
    #pragma unroll
    for (int k = 0; k < KR; k++)
        if (128 * k < ROWSPAN && rowdeg[k] > 0)
            atomicAdd(&sdeg[r0 + 128 * k], rowdeg[k]);
    __syncthreads();
    const int NA = (nAll > EACAP) ? EACAP : nAll;

    // v-side degrees (scattered LDS atomics over ~820 addresses)
    for (int e = tid; e < NA; e += 1024)
        atomicAdd(&sdeg[eAll[e] & 2047u], 1);
    __syncthreads();

    // core bitmap (local indices)
    for (int w = wv; w < NLCAP / 64; w += 16) {
        int l = w * 64 + lane;
        bool isc = (l < NN) && (sdeg[l] >= MIN_PTS);
        unsigned long long bm = __ballot(isc);
        if (lane == 0) corebm[w] = bm;
    }
    __syncthreads();
    auto corebit = [&](int l) -> bool { return (corebm[l >> 6] >> (l & 63)) & 1ull; };

    // classify eAll -> eL (core-core) / eB (core-noncore), wave-aggregated
    for (int e0 = 0; e0 < NA; e0 += 1024) {
        int e = e0 + tid;
        unsigned int pk = (e < NA) ? eAll[e] : 0u;
        bool val = (e < NA);
        int u = (int)(pk >> 11), v = (int)(pk & 2047u);
        bool cu = val && corebit(u), cv = val && corebit(v);
        bool isL = cu && cv, isB = val && (cu != cv);
        unsigned long long mL = __ballot(isL);
        if (mL) {
            int b0 = 0;
            if (lane == 0) b0 = atomicAdd(&nL, __popcll(mL));
            b0 = __shfl(b0, 0);
            if (isL) {
                int idx = b0 + __popcll(mL & ((1ull << lane) - 1ull));
                if (idx < ELCAP) eL[idx] = pk;
            }
        }
        unsigned long long mB = __ballot(isB);
        if (mB) {
            int b0 = 0;
            if (lane == 0) b0 = atomicAdd(&nB, __popcll(mB));
            b0 = __shfl(b0, 0);
            if (isB) {
                int idx = b0 + __popcll(mB & ((1ull << lane) - 1ull));
                if (idx < EBCAP) eB[idx] = pk;
            }
        }
    }
    __syncthreads();
    const int NL = (nL > ELCAP) ? ELCAP : nL;
    const int NB = (nB > EBCAP) ? EBCAP : nB;

    // SV rounds: hook-to-min + pointer jump (fixpoint = component min index)
    for (int r = 0; r < ROUNDS; r++) {
        if (tid == 0) sflag = 0;
        __syncthreads();
        for (int k = tid; k < NL; k += 1024) {
            unsigned int pk = eL[k];
            int u = (int)(pk >> 11), v = (int)(pk & 2047u);
            int a = spar[u], b2 = spar[v];
            if (a < b2)      { int old = atomicMin(&spar[v], a);  if (old > a)  sflag = 1; }
            else if (b2 < a) { int old = atomicMin(&spar[u], b2); if (old > b2) sflag = 1; }
        }
        __syncthreads();
        for (int k = tid; k < NN; k += 1024) {
            int s = spar[k]; int s2 = spar[s];
            if (s2 < s) { spar[k] = s2; sflag = 1; }
        }
        __syncthreads();
        if (!sflag) break;
    }

    // reps + rank (local order == global index order -> cid = rank among reps)
    for (int w = wv; w < NLCAP / 64; w += 16) {
        int l = w * 64 + lane;
        bool isr = (l < NN) && corebit(l) && (spar[l] == l);
        unsigned long long bm = __ballot(isr);
        if (lane == 0) repbm[w] = bm;
    }
    __syncthreads();
    if (wv == 0) {
        int running = 0;
        for (int w = 0; w < NLCAP / 64; w++) {
            unsigned long long bm = repbm[w];
            if ((bm >> lane) & 1ull)
                scid[w * 64 + lane] = running + __popcll(bm & ((1ull << lane) - 1ull));
            running += __popcll(bm);
        }
    }
    __syncthreads();
    // ccid -> overwrite spar
    int cc[2];
    #pragma unroll
    for (int t = 0; t < 2; t++) {
        int k = tid + t * 1024;
        cc[t] = (k < NN && corebit(k)) ? scid[spar[k]] : BIGC;
    }
    __syncthreads();
    #pragma unroll
    for (int t = 0; t < 2; t++) {
        int k = tid + t * 1024;
        if (k < NN) spar[k] = cc[t];
    }
    __syncthreads();
    // border: min adjacent core cid for the non-core endpoint
    for (int k = tid; k < NB; k += 1024) {
        unsigned int pk = eB[k];
        int u = (int)(pk >> 11), v = (int)(pk & 2047u);
        int cu = spar[u], cv = spar[v];
        if (cu == BIGC) atomicMin(&sbmin[u], cv);
        else            atomicMin(&sbmin[v], cu);
    }
    __syncthreads();
    // final labels + clustered output for this group's nodes
    for (int k = tid; k < NN; k += 1024) {
        int i = nlist[k];
        int c = spar[k];
        int lbl = (c != BIGC) ? c : ((sbmin[k] < BIGC) ? sbmin[k] : -1);
        out[i] = (float)lbl;
        const float* r = x + (size_t)i * XCOLS;
        float* o = out + NPTS + (size_t)i * 5;
        bool keep = lbl >= 0;
        #pragma unroll
        for (int c5 = 0; c5 < 5; c5++) o[c5] = keep ? r[c5] : 0.0f;
    }
}

extern "C" void kernel_launch(void* const* d_in, const int* in_sizes, int n_in,
                              void* d_out, int out_size, void* d_ws, size_t ws_size,
                              hipStream_t stream) {
    const float* x = (const float*)d_in[0];
    float* out = (float*)d_out;
    char* ws = (char*)d_ws;

    // workspace: 164 KB total
    float4* q = (float4*)(ws);               // 131072 B
    int* grp  = (int*)(ws + 131072);         // 32768 B

    k_setup<<<NPTS / 256, 256, 0, stream>>>(x, q, grp);
    k_group<<<NGROUPS, 1024, 0, stream>>>(q, grp, x, out);
}